// Round 8
// baseline (109.895 us; speedup 1.0000x reference)
//
#include <hip/hip_runtime.h>
#include <math.h>

#define NU_ 12000
#define NI_ 16000
#define NPU 12288   // padded Et stride (24 chunks * 512)
#define NPI 16384   // padded Et stride (32 chunks * 512)
#define DD 64
#define BB 1024
#define KC 512      // K-chunk (floats) per block iteration -> 2KB/row bursts
#define SPL 4       // K-splits; slices = 4*SPL = 16

typedef unsigned short ushort_t;
typedef __bf16 bf16x8 __attribute__((ext_vector_type(8)));
typedef float  f32x4  __attribute__((ext_vector_type(4)));
typedef unsigned short ushort4v __attribute__((ext_vector_type(4)));

static __device__ __forceinline__ ushort_t f2bf(float f) {
    __bf16 h = (__bf16)f;
    return __builtin_bit_cast(unsigned short, h);
}

// ---------------------------------------------------------------------------
// Kernel 0: transpose + cast E[N][64] f32 -> Et[64][Np] bf16, zero-padded
// columns N..Np (GEMM tail/stale-LDS reads multiply by exactly 0).
// ---------------------------------------------------------------------------
__global__ __launch_bounds__(256) void gde_transpose(
    const float* __restrict__ E, ushort_t* __restrict__ Et, int N, int Np)
{
    __shared__ ushort_t Ls[64][65];
    const int n0  = blockIdx.x * 64;
    const int tid = threadIdx.x;
    const int dg  = tid & 15;
    const int nr  = tid >> 4;
#pragma unroll
    for (int nn = 0; nn < 4; ++nn) {
        const int nl = nn * 16 + nr;
        const int n  = n0 + nl;
        float4 v = make_float4(0.f, 0.f, 0.f, 0.f);
        if (n < N) v = *(const float4*)(E + (size_t)n * DD + dg * 4);
        Ls[nl][dg * 4 + 0] = f2bf(v.x);
        Ls[nl][dg * 4 + 1] = f2bf(v.y);
        Ls[nl][dg * 4 + 2] = f2bf(v.z);
        Ls[nl][dg * 4 + 3] = f2bf(v.w);
    }
    __syncthreads();
    const int d   = tid & 63;
    const int nl0 = (tid >> 6) * 16;
#pragma unroll
    for (int g = 0; g < 4; ++g) {
        ushort4v t;
#pragma unroll
        for (int i = 0; i < 4; ++i) t[i] = Ls[nl0 + g * 4 + i][d];
        *(ushort4v*)(Et + (size_t)d * Np + n0 + nl0 + g * 4) = t;
    }
}

// ---------------------------------------------------------------------------
// Kernel 1: gathered+masked GEMM. Round-6 counted-vmcnt raw-barrier pipeline,
// KC=512 (2KB contiguous per row-visit — DRAM burst-length probe).
// Block: 16 rows x 64 d. Wave stages 4 rows (2 float4 L + 2 float4 M each);
// computes 4 k-steps x 4 d-frags on the block's single 16-row A-frag.
// ---------------------------------------------------------------------------
__global__ __launch_bounds__(256, 2) void gde_gemm(
    const float* __restrict__ L_u, const float* __restrict__ L_i,
    const ushort_t* __restrict__ EtU, const ushort_t* __restrict__ EtI,
    const float* __restrict__ mu,  const float* __restrict__ mp,
    const float* __restrict__ mn,
    const int* __restrict__ user, const int* __restrict__ pos,
    const int* __restrict__ nega,
    float* __restrict__ P, int S)
{
    __shared__ ushort_t As[16 * 512];   // 16 KB, row stride 1024B, swizzled

    const int rt  = blockIdx.x;   // 0..63: 16-row tile
    const int s   = blockIdx.y;   // 0..S-1
    const int j   = blockIdx.z;   // 0=user,1=pos,2=nega
    const int tid = threadIdx.x;
    const int w   = tid >> 6;
    const int l   = tid & 63;

    const float* L; const ushort_t* Et; const float* M; const int* idx;
    int N, Np;
    if (j == 0)      { L = L_u; Et = EtU; M = mu; idx = user; N = NU_; Np = NPU; }
    else if (j == 1) { L = L_i; Et = EtI; M = mp; idx = pos;  N = NI_; Np = NPI; }
    else             { L = L_i; Et = EtI; M = mn; idx = nega; N = NI_; Np = NPI; }

    const int base = rt * 16;
    unsigned int Loff[4], Moff[4];            // byte offsets (max ~1.02GB, fits u32)
#pragma unroll
    for (int r = 0; r < 4; ++r) {
        const int row = base + w * 4 + r;
        Loff[r] = (unsigned int)idx[row] * (unsigned int)(N * 4);
        Moff[r] = (unsigned int)row * (unsigned int)(N * 4);
    }

    const int dcol = l & 15;
    const int g4   = l >> 4;
    const ushort_t* Eb[4];
#pragma unroll
    for (int df = 0; df < 4; ++df) Eb[df] = Et + (size_t)(df * 16 + dcol) * Np;

    f32x4 acc[4];
#pragma unroll
    for (int i = 0; i < 4; ++i) acc[i] = (f32x4){0.f, 0.f, 0.f, 0.f};

    const int nc  = (N + KC - 1) / KC;        // 24 or 32
    const int kb0 = (s * nc) / S;
    const int kb1 = ((s + 1) * nc) / S;

    float4 La[4][2], Ma[4][2];
#pragma unroll
    for (int r = 0; r < 4; ++r) {
        La[r][0] = La[r][1] = make_float4(0.f,0.f,0.f,0.f);
        Ma[r][0] = Ma[r][1] = La[r][0];
    }

    // ---- prologue: issue chunk kb0's loads (2KB per row, back-to-back)
    {
        const int kg = kb0 * KC + 8 * l;      // lane's 8-float window
        if (kg < N) {                          // N%8==0 -> whole window valid
            const size_t boff = (size_t)kg * 4u;
#pragma unroll
            for (int r = 0; r < 4; ++r) {
                La[r][0] = *(const float4*)((const char*)L + Loff[r] + boff);
                La[r][1] = *(const float4*)((const char*)L + Loff[r] + boff + 16);
                Ma[r][0] = *(const float4*)((const char*)M + Moff[r] + boff);
                Ma[r][1] = *(const float4*)((const char*)M + Moff[r] + boff + 16);
            }
        }
    }

    for (int kb = kb0; kb < kb1; ++kb) {
        // ---- STORE: select + convert current chunk regs -> swizzled LDS
        //      (compiler's counted vmcnt wait for La/Ma lands here)
#pragma unroll
        for (int r = 0; r < 4; ++r) {
            const int row = w * 4 + r;
            bf16x8 af;
            af[0] = (Ma[r][0].x >= 0.1f) ? (__bf16)La[r][0].x : (__bf16)0.0f;
            af[1] = (Ma[r][0].y >= 0.1f) ? (__bf16)La[r][0].y : (__bf16)0.0f;
            af[2] = (Ma[r][0].z >= 0.1f) ? (__bf16)La[r][0].z : (__bf16)0.0f;
            af[3] = (Ma[r][0].w >= 0.1f) ? (__bf16)La[r][0].w : (__bf16)0.0f;
            af[4] = (Ma[r][1].x >= 0.1f) ? (__bf16)La[r][1].x : (__bf16)0.0f;
            af[5] = (Ma[r][1].y >= 0.1f) ? (__bf16)La[r][1].y : (__bf16)0.0f;
            af[6] = (Ma[r][1].z >= 0.1f) ? (__bf16)La[r][1].z : (__bf16)0.0f;
            af[7] = (Ma[r][1].w >= 0.1f) ? (__bf16)La[r][1].w : (__bf16)0.0f;
            *(bf16x8*)((char*)As + (row << 10) + ((l * 16) ^ ((row & 7) << 4))) = af;
        }

        // ---- Et B-frag preload for THIS chunk (L2-resident) -> regs.
        //      Issued BEFORE next-chunk staging so compute's wait is counted.
        bf16x8 bfr[4][4];
#pragma unroll
        for (int h = 0; h < 4; ++h) {
            const int kk = kb * KC + (4 * w + h) * 32 + 8 * g4;
#pragma unroll
            for (int df = 0; df < 4; ++df)
                bfr[h][df] = *(const bf16x8*)(Eb[df] + kk);
        }
        asm volatile("" ::: "memory");   // pin Et-issue before staging-issue

        // ---- ISSUE next chunk's loads (stay in flight across the barrier)
        if (kb + 1 < kb1) {
            const int kg = (kb + 1) * KC + 8 * l;
            if (kg < N) {
                const size_t boff = (size_t)kg * 4u;
#pragma unroll
                for (int r = 0; r < 4; ++r) {
                    La[r][0] = *(const float4*)((const char*)L + Loff[r] + boff);
                    La[r][1] = *(const float4*)((const char*)L + Loff[r] + boff + 16);
                    Ma[r][0] = *(const float4*)((const char*)M + Moff[r] + boff);
                    Ma[r][1] = *(const float4*)((const char*)M + Moff[r] + boff + 16);
                }
            }
            // stale lanes keep finite regs; Et zero-pad nullifies their product
        }

        // ---- barrier WITHOUT vmcnt drain (raw s_barrier, lgkm only)
        asm volatile("s_waitcnt lgkmcnt(0)" ::: "memory");
        __builtin_amdgcn_s_barrier();
        asm volatile("" ::: "memory");

        // ---- COMPUTE: wave w covers k-steps 4w..4w+3 of this chunk
#pragma unroll
        for (int h = 0; h < 4; ++h) {
            const int ks = 4 * w + h;
            const int cb = 64 * ks + 16 * g4;          // byte offset in LDS row
            const int r0 = dcol;
            const bf16x8 af = *(const bf16x8*)((char*)As + (r0 << 10) +
                                               (cb ^ ((r0 & 7) << 4)));
            acc[0] = __builtin_amdgcn_mfma_f32_16x16x32_bf16(af, bfr[h][0], acc[0], 0, 0, 0);
            acc[1] = __builtin_amdgcn_mfma_f32_16x16x32_bf16(af, bfr[h][1], acc[1], 0, 0, 0);
            acc[2] = __builtin_amdgcn_mfma_f32_16x16x32_bf16(af, bfr[h][2], acc[2], 0, 0, 0);
            acc[3] = __builtin_amdgcn_mfma_f32_16x16x32_bf16(af, bfr[h][3], acc[3], 0, 0, 0);
        }

        // ---- protect LDS from next iter's STORE
        asm volatile("" ::: "memory");
        __builtin_amdgcn_s_barrier();
        asm volatile("" ::: "memory");
    }

    // ---- write partial: slice seff = s*4 + w (wave's 4 k-steps, all chunks)
    float* Pb = P + ((size_t)(j * (S * 4) + s * 4 + w) * BB + base) * DD;
#pragma unroll
    for (int ri = 0; ri < 4; ++ri) {
        const int m = g4 * 4 + ri;
        Pb[(size_t)m * DD +  0 + dcol] = acc[0][ri];
        Pb[(size_t)m * DD + 16 + dcol] = acc[1][ri];
        Pb[(size_t)m * DD + 32 + dcol] = acc[2][ri];
        Pb[(size_t)m * DD + 48 + dcol] = acc[3][ri];
    }
}

// ---------------------------------------------------------------------------
// Kernel 2: per-batch-row finalize (4 rows per 256-thread block).
// ---------------------------------------------------------------------------
__global__ __launch_bounds__(256) void gde_finalize(
    const float* __restrict__ P, int Seff,
    float* __restrict__ term, float* __restrict__ regp)
{
    const int b    = blockIdx.x * 4 + (threadIdx.x >> 6);
    const int lane = threadIdx.x & 63;
    const size_t joff = (size_t)Seff * BB * DD;

    float fu = 0.f, fp_ = 0.f, fn = 0.f;
    for (int s = 0; s < Seff; ++s) {
        const size_t base = ((size_t)s * BB + b) * DD + lane;
        fu  += P[base];
        fp_ += P[base + joff];
        fn  += P[base + 2 * joff];
    }

    float rp = fu * fp_;
    float rn = fu * fn;
    float rg = fu * fu + fp_ * fp_ + fn * fn;
#pragma unroll
    for (int o = 32; o > 0; o >>= 1) {
        rp += __shfl_xor(rp, o);
        rn += __shfl_xor(rn, o);
        rg += __shfl_xor(rg, o);
    }

    if (lane == 0) {
        const float sn = 1.0f / (1.0f + expf(-rn));
        const float w  = 1.0f - log10f(1.0f - fminf(sn, 0.99f));
        const float x  = rp - w * rn;
        const float t  = -x;   // -log(sigmoid(x)) = softplus(-x), finite
        term[b] = fmaxf(t, 0.0f) + log1pf(expf(-fabsf(t)));
        regp[b] = rg;
    }
}

// ---------------------------------------------------------------------------
// Kernel 3: deterministic scalar reduction.
// ---------------------------------------------------------------------------
__global__ __launch_bounds__(256) void gde_reduce(
    const float* __restrict__ term, const float* __restrict__ regp,
    float* __restrict__ out)
{
    __shared__ float sm[256];
    const int t = threadIdx.x;
    float v = 0.f;
    for (int i = t; i < BB; i += 256)
        v += term[i] + 0.01f * regp[i];
    sm[t] = v;
    __syncthreads();
    for (int o = 128; o > 0; o >>= 1) {
        if (t < o) sm[t] += sm[t + o];
        __syncthreads();
    }
    if (t == 0) out[0] = sm[0] / (float)BB;
}

extern "C" void kernel_launch(void* const* d_in, const int* in_sizes, int n_in,
                              void* d_out, int out_size, void* d_ws, size_t ws_size,
                              hipStream_t stream)
{
    const float* L_u = (const float*)d_in[0];
    const float* L_i = (const float*)d_in[1];
    const float* ue  = (const float*)d_in[2];
    const float* ie  = (const float*)d_in[3];
    const float* mu  = (const float*)d_in[4];
    const float* mp  = (const float*)d_in[5];
    const float* mn  = (const float*)d_in[6];
    const int* user  = (const int*)d_in[7];
    const int* pos   = (const int*)d_in[8];
    const int* nega  = (const int*)d_in[9];
    float* out = (float*)d_out;

    const size_t etU_b  = (size_t)DD * NPU * 2;
    const size_t etI_b  = (size_t)DD * NPI * 2;
    const size_t slice  = (size_t)3 * BB * DD * 4;    // per-seff P bytes
    const size_t fixed  = etU_b + etI_b + 2 * BB * 4 + 512;
    int S = SPL;
    while (S > 1 && (size_t)(4 * S) * slice + fixed > ws_size) --S;
    const int Seff = 4 * S;

    float*    P    = (float*)d_ws;
    ushort_t* EtU  = (ushort_t*)((char*)d_ws + (size_t)Seff * slice);
    ushort_t* EtI  = (ushort_t*)((char*)EtU + etU_b);
    float*    term = (float*)((char*)EtI + etI_b);
    float*    regp = term + BB;

    gde_transpose<<<dim3(NPU / 64), dim3(256), 0, stream>>>(ue, EtU, NU_, NPU);
    gde_transpose<<<dim3(NPI / 64), dim3(256), 0, stream>>>(ie, EtI, NI_, NPI);

    gde_gemm<<<dim3(64, S, 3), dim3(256), 0, stream>>>(
        L_u, L_i, EtU, EtI, mu, mp, mn, user, pos, nega, P, S);

    gde_finalize<<<dim3(BB / 4), dim3(256), 0, stream>>>(P, Seff, term, regp);
    gde_reduce<<<dim3(1), dim3(256), 0, stream>>>(term, regp, out);
}

// Round 9
// 95.317 us; speedup vs baseline: 1.1529x; 1.1529x over previous
//
#include <hip/hip_runtime.h>
#include <math.h>

#define NU_ 12000
#define NI_ 16000
#define NPU 12288   // padded Et stride
#define NPI 16384   // padded Et stride
#define DD 64
#define BB 1024
#define KC 256      // K-chunk (floats) per block iteration
#define SPL 8

typedef unsigned short ushort_t;
typedef __bf16 bf16x8 __attribute__((ext_vector_type(8)));
typedef float  f32x4  __attribute__((ext_vector_type(4)));
typedef float  f4v    __attribute__((ext_vector_type(4)));
typedef unsigned short ushort4v __attribute__((ext_vector_type(4)));

static __device__ __forceinline__ ushort_t f2bf(float f) {
    __bf16 h = (__bf16)f;
    return __builtin_bit_cast(unsigned short, h);
}
static __device__ __forceinline__ f4v ntload(const void* p) {
    return __builtin_nontemporal_load((const f4v*)p);   // nt: no L2 allocate
}

// ---------------------------------------------------------------------------
// Kernel 0: transpose + cast E[N][64] f32 -> Et[64][Np] bf16, zero-padded
// columns N..Np (GEMM tail/stale-LDS reads multiply by exactly 0).
// ---------------------------------------------------------------------------
__global__ __launch_bounds__(256) void gde_transpose(
    const float* __restrict__ E, ushort_t* __restrict__ Et, int N, int Np)
{
    __shared__ ushort_t Ls[64][65];
    const int n0  = blockIdx.x * 64;
    const int tid = threadIdx.x;
    const int dg  = tid & 15;
    const int nr  = tid >> 4;
#pragma unroll
    for (int nn = 0; nn < 4; ++nn) {
        const int nl = nn * 16 + nr;
        const int n  = n0 + nl;
        float4 v = make_float4(0.f, 0.f, 0.f, 0.f);
        if (n < N) v = *(const float4*)(E + (size_t)n * DD + dg * 4);
        Ls[nl][dg * 4 + 0] = f2bf(v.x);
        Ls[nl][dg * 4 + 1] = f2bf(v.y);
        Ls[nl][dg * 4 + 2] = f2bf(v.z);
        Ls[nl][dg * 4 + 3] = f2bf(v.w);
    }
    __syncthreads();
    const int d   = tid & 63;
    const int nl0 = (tid >> 6) * 16;
#pragma unroll
    for (int g = 0; g < 4; ++g) {
        ushort4v t;
#pragma unroll
        for (int i = 0; i < 4; ++i) t[i] = Ls[nl0 + g * 4 + i][d];
        *(ushort4v*)(Et + (size_t)d * Np + n0 + nl0 + g * 4) = t;
    }
}

// ---------------------------------------------------------------------------
// Kernel 1: gathered+masked GEMM (round-6 winning structure) + cross-wave
// LDS reduction epilogue (one P slice per block: Seff = S).
// ---------------------------------------------------------------------------
__global__ __launch_bounds__(256, 2) void gde_gemm(
    const float* __restrict__ L_u, const float* __restrict__ L_i,
    const ushort_t* __restrict__ EtU, const ushort_t* __restrict__ EtI,
    const float* __restrict__ mu,  const float* __restrict__ mp,
    const float* __restrict__ mn,
    const int* __restrict__ user, const int* __restrict__ pos,
    const int* __restrict__ nega,
    float* __restrict__ P, int S)
{
    // 16KB As staging tile, later aliased by 33.3KB reduce buffer
    __shared__ __align__(16) char smem[4 * 32 * 65 * 4];

    const int rt  = blockIdx.x;   // 0..31
    const int s   = blockIdx.y;   // 0..S-1
    const int j   = blockIdx.z;   // 0=user,1=pos,2=nega
    const int tid = threadIdx.x;
    const int w   = tid >> 6;
    const int l   = tid & 63;

    const float* L; const ushort_t* Et; const float* M; const int* idx;
    int N, Np;
    if (j == 0)      { L = L_u; Et = EtU; M = mu; idx = user; N = NU_; Np = NPU; }
    else if (j == 1) { L = L_i; Et = EtI; M = mp; idx = pos;  N = NI_; Np = NPI; }
    else             { L = L_i; Et = EtI; M = mn; idx = nega; N = NI_; Np = NPI; }

    const int base = rt * 32;
    unsigned int Loff[8], Moff[8];            // byte offsets (max ~1.02GB)
#pragma unroll
    for (int r = 0; r < 8; ++r) {
        const int row = base + w * 8 + r;
        Loff[r] = (unsigned int)idx[row] * (unsigned int)(N * 4);
        Moff[r] = (unsigned int)row * (unsigned int)(N * 4);
    }

    const int dcol = l & 15;
    const int g4   = l >> 4;
    const ushort_t* Eb[4];
#pragma unroll
    for (int df = 0; df < 4; ++df) Eb[df] = Et + (size_t)(df * 16 + dcol) * Np;

    f32x4 acc[8];
#pragma unroll
    for (int i = 0; i < 8; ++i) acc[i] = (f32x4){0.f, 0.f, 0.f, 0.f};

    const int nc  = (N + KC - 1) / KC;        // 47 or 63
    const int kb0 = (s * nc) / S;
    const int kb1 = ((s + 1) * nc) / S;

    f4v La[8], Ma[8];
#pragma unroll
    for (int r = 0; r < 8; ++r) { La[r] = (f4v){0.f,0.f,0.f,0.f}; Ma[r] = La[r]; }

    // ---- prologue: issue chunk kb0's 16 loads (per-lane OOB-guarded)
    {
        const int kg = kb0 * KC + 4 * l;
        if (kg < N) {
            const size_t boff = (size_t)kg * 4u;
#pragma unroll
            for (int r = 0; r < 8; ++r) {
                La[r] = ntload((const char*)L + Loff[r] + boff);
                Ma[r] = ntload((const char*)M + Moff[r] + boff);
            }
        }
    }

    for (int kb = kb0; kb < kb1; ++kb) {
        // ---- STORE: select+convert current chunk regs -> swizzled LDS
        //      (compiler's counted vmcnt wait for La/Ma lands here)
#pragma unroll
        for (int r = 0; r < 8; ++r) {
            const int row = w * 8 + r;
            ushort4v t;
            t[0] = (Ma[r][0] >= 0.1f) ? f2bf(La[r][0]) : (ushort_t)0;
            t[1] = (Ma[r][1] >= 0.1f) ? f2bf(La[r][1]) : (ushort_t)0;
            t[2] = (Ma[r][2] >= 0.1f) ? f2bf(La[r][2]) : (ushort_t)0;
            t[3] = (Ma[r][3] >= 0.1f) ? f2bf(La[r][3]) : (ushort_t)0;
            *(ushort4v*)(smem + (row << 9) + ((l * 8) ^ ((row & 7) << 4))) = t;
        }

        // ---- Et B-frag preload for THIS chunk (L2-resident) -> regs.
        //      Issued BEFORE next-chunk staging so compute's wait is counted.
        bf16x8 bfr[2][4];
#pragma unroll
        for (int h = 0; h < 2; ++h) {
            const int kk = kb * KC + (2 * w + h) * 32 + 8 * g4;
#pragma unroll
            for (int df = 0; df < 4; ++df)
                bfr[h][df] = *(const bf16x8*)(Eb[df] + kk);
        }
        asm volatile("" ::: "memory");   // pin Et-issue before staging-issue

        // ---- ISSUE next chunk's 16 loads (stay in flight across the barrier)
        if (kb + 1 < kb1) {
            const int kg = (kb + 1) * KC + 4 * l;
            if (kg < N) {
                const size_t boff = (size_t)kg * 4u;
#pragma unroll
                for (int r = 0; r < 8; ++r) {
                    La[r] = ntload((const char*)L + Loff[r] + boff);
                    Ma[r] = ntload((const char*)M + Moff[r] + boff);
                }
            }
            // stale lanes keep finite regs; Et zero-pad nullifies their product
        }

        // ---- barrier WITHOUT vmcnt drain (raw s_barrier, lgkm only)
        asm volatile("s_waitcnt lgkmcnt(0)" ::: "memory");
        __builtin_amdgcn_s_barrier();
        asm volatile("" ::: "memory");

        // ---- COMPUTE: wave w covers k-steps 2w, 2w+1 of this chunk
#pragma unroll
        for (int h = 0; h < 2; ++h) {
            const int ks = 2 * w + h;
            const int cb = 64 * ks + 16 * g4;          // byte offset in LDS row
            const int r0 = dcol, r1 = 16 + dcol;
            const bf16x8 af0 = *(const bf16x8*)(smem + (r0 << 9) + (cb ^ ((r0 & 7) << 4)));
            const bf16x8 af1 = *(const bf16x8*)(smem + (r1 << 9) + (cb ^ ((r1 & 7) << 4)));
            acc[0] = __builtin_amdgcn_mfma_f32_16x16x32_bf16(af0, bfr[h][0], acc[0], 0, 0, 0);
            acc[1] = __builtin_amdgcn_mfma_f32_16x16x32_bf16(af0, bfr[h][1], acc[1], 0, 0, 0);
            acc[2] = __builtin_amdgcn_mfma_f32_16x16x32_bf16(af0, bfr[h][2], acc[2], 0, 0, 0);
            acc[3] = __builtin_amdgcn_mfma_f32_16x16x32_bf16(af0, bfr[h][3], acc[3], 0, 0, 0);
            acc[4] = __builtin_amdgcn_mfma_f32_16x16x32_bf16(af1, bfr[h][0], acc[4], 0, 0, 0);
            acc[5] = __builtin_amdgcn_mfma_f32_16x16x32_bf16(af1, bfr[h][1], acc[5], 0, 0, 0);
            acc[6] = __builtin_amdgcn_mfma_f32_16x16x32_bf16(af1, bfr[h][2], acc[6], 0, 0, 0);
            acc[7] = __builtin_amdgcn_mfma_f32_16x16x32_bf16(af1, bfr[h][3], acc[7], 0, 0, 0);
        }

        // ---- protect LDS from next iter's STORE
        asm volatile("" ::: "memory");
        __builtin_amdgcn_s_barrier();
        asm volatile("" ::: "memory");
    }

    // ---- cross-wave reduction: sum the 4 k-quarter accs -> ONE P slice/block
    __syncthreads();                       // done with As region
    float* Rs = (float*)smem;              // [4][32][65] floats, +1 pad stagger
#pragma unroll
    for (int fi = 0; fi < 8; ++fi) {
#pragma unroll
        for (int ri = 0; ri < 4; ++ri) {
            const int row = ((fi >> 2) << 4) + g4 * 4 + ri;
            const int col = ((fi & 3) << 4) + dcol;
            Rs[(w * 32 + row) * 65 + col] = acc[fi][ri];
        }
    }
    __syncthreads();
    {
        const int row  = tid >> 3;         // 0..31
        const int colg = (tid & 7) * 8;    // 0,8,..56
        float v[8];
#pragma unroll
        for (int i = 0; i < 8; ++i) {
            v[i] = Rs[(0 * 32 + row) * 65 + colg + i]
                 + Rs[(1 * 32 + row) * 65 + colg + i]
                 + Rs[(2 * 32 + row) * 65 + colg + i]
                 + Rs[(3 * 32 + row) * 65 + colg + i];
        }
        float* Pb = P + ((size_t)(j * S + s) * BB + base + row) * DD + colg;
        *(float4*)(Pb + 0) = make_float4(v[0], v[1], v[2], v[3]);
        *(float4*)(Pb + 4) = make_float4(v[4], v[5], v[6], v[7]);
    }
}

// ---------------------------------------------------------------------------
// Kernel 2: per-batch-row finalize (4 rows per 256-thread block).
// ---------------------------------------------------------------------------
__global__ __launch_bounds__(256) void gde_finalize(
    const float* __restrict__ P, int Seff,
    float* __restrict__ term, float* __restrict__ regp)
{
    const int b    = blockIdx.x * 4 + (threadIdx.x >> 6);
    const int lane = threadIdx.x & 63;
    const size_t joff = (size_t)Seff * BB * DD;

    float fu = 0.f, fp_ = 0.f, fn = 0.f;
    for (int s = 0; s < Seff; ++s) {
        const size_t base = ((size_t)s * BB + b) * DD + lane;
        fu  += P[base];
        fp_ += P[base + joff];
        fn  += P[base + 2 * joff];
    }

    float rp = fu * fp_;
    float rn = fu * fn;
    float rg = fu * fu + fp_ * fp_ + fn * fn;
#pragma unroll
    for (int o = 32; o > 0; o >>= 1) {
        rp += __shfl_xor(rp, o);
        rn += __shfl_xor(rn, o);
        rg += __shfl_xor(rg, o);
    }

    if (lane == 0) {
        const float sn = 1.0f / (1.0f + expf(-rn));
        const float w  = 1.0f - log10f(1.0f - fminf(sn, 0.99f));
        const float x  = rp - w * rn;
        const float t  = -x;   // -log(sigmoid(x)) = softplus(-x), finite
        term[b] = fmaxf(t, 0.0f) + log1pf(expf(-fabsf(t)));
        regp[b] = rg;
    }
}

// ---------------------------------------------------------------------------
// Kernel 3: deterministic scalar reduction.
// ---------------------------------------------------------------------------
__global__ __launch_bounds__(256) void gde_reduce(
    const float* __restrict__ term, const float* __restrict__ regp,
    float* __restrict__ out)
{
    __shared__ float sm[256];
    const int t = threadIdx.x;
    float v = 0.f;
    for (int i = t; i < BB; i += 256)
        v += term[i] + 0.01f * regp[i];
    sm[t] = v;
    __syncthreads();
    for (int o = 128; o > 0; o >>= 1) {
        if (t < o) sm[t] += sm[t + o];
        __syncthreads();
    }
    if (t == 0) out[0] = sm[0] / (float)BB;
}

extern "C" void kernel_launch(void* const* d_in, const int* in_sizes, int n_in,
                              void* d_out, int out_size, void* d_ws, size_t ws_size,
                              hipStream_t stream)
{
    const float* L_u = (const float*)d_in[0];
    const float* L_i = (const float*)d_in[1];
    const float* ue  = (const float*)d_in[2];
    const float* ie  = (const float*)d_in[3];
    const float* mu  = (const float*)d_in[4];
    const float* mp  = (const float*)d_in[5];
    const float* mn  = (const float*)d_in[6];
    const int* user  = (const int*)d_in[7];
    const int* pos   = (const int*)d_in[8];
    const int* nega  = (const int*)d_in[9];
    float* out = (float*)d_out;

    const size_t etU_b  = (size_t)DD * NPU * 2;
    const size_t etI_b  = (size_t)DD * NPI * 2;
    const size_t slice  = (size_t)3 * BB * DD * 4;    // per-slice P bytes
    const size_t fixed  = etU_b + etI_b + 2 * BB * 4 + 512;
    int S = SPL;
    while (S > 1 && (size_t)S * slice + fixed > ws_size) --S;

    float*    P    = (float*)d_ws;
    ushort_t* EtU  = (ushort_t*)((char*)d_ws + (size_t)S * slice);
    ushort_t* EtI  = (ushort_t*)((char*)EtU + etU_b);
    float*    term = (float*)((char*)EtI + etI_b);
    float*    regp = term + BB;

    gde_transpose<<<dim3(NPU / 64), dim3(256), 0, stream>>>(ue, EtU, NU_, NPU);
    gde_transpose<<<dim3(NPI / 64), dim3(256), 0, stream>>>(ie, EtI, NI_, NPI);

    gde_gemm<<<dim3(32, S, 3), dim3(256), 0, stream>>>(
        L_u, L_i, EtU, EtI, mu, mp, mn, user, pos, nega, P, S);

    gde_finalize<<<dim3(BB / 4), dim3(256), 0, stream>>>(P, S, term, regp);
    gde_reduce<<<dim3(1), dim3(256), 0, stream>>>(term, regp, out);
}

// Round 10
// 92.426 us; speedup vs baseline: 1.1890x; 1.0313x over previous
//
#include <hip/hip_runtime.h>
#include <math.h>

#define NU_ 12000
#define NI_ 16000
#define NPU 12288   // padded Et stride
#define NPI 16384   // padded Et stride
#define DD 64
#define BB 1024
#define KC 256      // K-chunk (floats) per block iteration
#define SPL 8

typedef unsigned short ushort_t;
typedef __bf16 bf16x8 __attribute__((ext_vector_type(8)));
typedef float  f32x4  __attribute__((ext_vector_type(4)));
typedef float  f4v    __attribute__((ext_vector_type(4)));
typedef unsigned short ushort4v __attribute__((ext_vector_type(4)));

static __device__ __forceinline__ ushort_t f2bf(float f) {
    __bf16 h = (__bf16)f;
    return __builtin_bit_cast(unsigned short, h);
}
static __device__ __forceinline__ f4v ntload(const void* p) {
    return __builtin_nontemporal_load((const f4v*)p);   // nt: no L2 allocate
}

// ---------------------------------------------------------------------------
// Kernel 0: transpose + cast E[N][64] f32 -> Et[64][Np] bf16, zero-padded
// columns N..Np (GEMM tail/stale-LDS reads multiply by exactly 0).
// ---------------------------------------------------------------------------
__global__ __launch_bounds__(256) void gde_transpose(
    const float* __restrict__ E, ushort_t* __restrict__ Et, int N, int Np)
{
    __shared__ ushort_t Ls[64][65];
    const int n0  = blockIdx.x * 64;
    const int tid = threadIdx.x;
    const int dg  = tid & 15;
    const int nr  = tid >> 4;
#pragma unroll
    for (int nn = 0; nn < 4; ++nn) {
        const int nl = nn * 16 + nr;
        const int n  = n0 + nl;
        float4 v = make_float4(0.f, 0.f, 0.f, 0.f);
        if (n < N) v = *(const float4*)(E + (size_t)n * DD + dg * 4);
        Ls[nl][dg * 4 + 0] = f2bf(v.x);
        Ls[nl][dg * 4 + 1] = f2bf(v.y);
        Ls[nl][dg * 4 + 2] = f2bf(v.z);
        Ls[nl][dg * 4 + 3] = f2bf(v.w);
    }
    __syncthreads();
    const int d   = tid & 63;
    const int nl0 = (tid >> 6) * 16;
#pragma unroll
    for (int g = 0; g < 4; ++g) {
        ushort4v t;
#pragma unroll
        for (int i = 0; i < 4; ++i) t[i] = Ls[nl0 + g * 4 + i][d];
        *(ushort4v*)(Et + (size_t)d * Np + n0 + nl0 + g * 4) = t;
    }
}

// ---------------------------------------------------------------------------
// Kernel 1: gathered+masked GEMM (R6/R9 pipeline) at 3 blocks/CU.
// VGPR diet: Et h=0 frags preloaded (16 regs), h=1 frags loaded inside the
// compute phase; single per-lane Et base. LPT 1D grid: long (item) blocks
// first, user blocks last; 768 blocks = one full residency round at 3/CU.
// ---------------------------------------------------------------------------
__global__ __launch_bounds__(256, 3) void gde_gemm(
    const float* __restrict__ L_u, const float* __restrict__ L_i,
    const ushort_t* __restrict__ EtU, const ushort_t* __restrict__ EtI,
    const float* __restrict__ mu,  const float* __restrict__ mp,
    const float* __restrict__ mn,
    const int* __restrict__ user, const int* __restrict__ pos,
    const int* __restrict__ nega,
    float* __restrict__ P, int S)
{
    // 16KB As staging tile, later aliased by 33.3KB reduce buffer
    __shared__ __align__(16) char smem[4 * 32 * 65 * 4];

    // ---- LPT decode: bid<512 -> j=1,2 (8 chunks); bid>=512 -> j=0 (6 chunks)
    const int bid = blockIdx.x;
    int j, idx;
    if (bid < 512) { j = 1 + (bid >> 8); idx = bid & 255; }
    else           { j = 0;              idx = bid - 512; }
    const int rt = idx & 31;      // 0..31
    const int s  = idx >> 5;      // 0..7

    const int tid = threadIdx.x;
    const int w   = tid >> 6;
    const int l   = tid & 63;

    const float* L; const ushort_t* Et; const float* M; const int* idx_;
    int N, Np;
    if (j == 0)      { L = L_u; Et = EtU; M = mu; idx_ = user; N = NU_; Np = NPU; }
    else if (j == 1) { L = L_i; Et = EtI; M = mp; idx_ = pos;  N = NI_; Np = NPI; }
    else             { L = L_i; Et = EtI; M = mn; idx_ = nega; N = NI_; Np = NPI; }

    const int base = rt * 32;
    unsigned int Loff[8], Moff[8];            // byte offsets (max ~1.02GB)
#pragma unroll
    for (int r = 0; r < 8; ++r) {
        const int row = base + w * 8 + r;
        Loff[r] = (unsigned int)idx_[row] * (unsigned int)(N * 4);
        Moff[r] = (unsigned int)row * (unsigned int)(N * 4);
    }

    const int dcol = l & 15;
    const int g4   = l >> 4;
    const ushort_t* EbBase = Et + (size_t)dcol * Np;   // + df*16*Np + kk
    const size_t dfs = (size_t)16 * Np;

    f32x4 acc[8];
#pragma unroll
    for (int i = 0; i < 8; ++i) acc[i] = (f32x4){0.f, 0.f, 0.f, 0.f};

    const int nc  = (N + KC - 1) / KC;        // 47 or 63
    const int kb0 = (s * nc) / S;
    const int kb1 = ((s + 1) * nc) / S;

    f4v La[8], Ma[8];
#pragma unroll
    for (int r = 0; r < 8; ++r) { La[r] = (f4v){0.f,0.f,0.f,0.f}; Ma[r] = La[r]; }

    // ---- prologue: issue chunk kb0's 16 loads (per-lane OOB-guarded)
    {
        const int kg = kb0 * KC + 4 * l;
        if (kg < N) {
            const size_t boff = (size_t)kg * 4u;
#pragma unroll
            for (int r = 0; r < 8; ++r) {
                La[r] = ntload((const char*)L + Loff[r] + boff);
                Ma[r] = ntload((const char*)M + Moff[r] + boff);
            }
        }
    }

    for (int kb = kb0; kb < kb1; ++kb) {
        // ---- STORE: select+convert current chunk regs -> swizzled LDS
        //      (compiler's counted vmcnt wait for La/Ma lands here)
#pragma unroll
        for (int r = 0; r < 8; ++r) {
            const int row = w * 8 + r;
            ushort4v t;
            t[0] = (Ma[r][0] >= 0.1f) ? f2bf(La[r][0]) : (ushort_t)0;
            t[1] = (Ma[r][1] >= 0.1f) ? f2bf(La[r][1]) : (ushort_t)0;
            t[2] = (Ma[r][2] >= 0.1f) ? f2bf(La[r][2]) : (ushort_t)0;
            t[3] = (Ma[r][3] >= 0.1f) ? f2bf(La[r][3]) : (ushort_t)0;
            *(ushort4v*)(smem + (row << 9) + ((l * 8) ^ ((row & 7) << 4))) = t;
        }

        // ---- Et h=0 B-frags preload (L2-resident) -> 16 regs.
        bf16x8 bfr0[4];
        {
            const int kk = kb * KC + (2 * w) * 32 + 8 * g4;
#pragma unroll
            for (int df = 0; df < 4; ++df)
                bfr0[df] = *(const bf16x8*)(EbBase + df * dfs + kk);
        }
        asm volatile("" ::: "memory");   // pin Et-issue before staging-issue

        // ---- ISSUE next chunk's 16 loads (stay in flight across the barrier)
        if (kb + 1 < kb1) {
            const int kg = (kb + 1) * KC + 4 * l;
            if (kg < N) {
                const size_t boff = (size_t)kg * 4u;
#pragma unroll
                for (int r = 0; r < 8; ++r) {
                    La[r] = ntload((const char*)L + Loff[r] + boff);
                    Ma[r] = ntload((const char*)M + Moff[r] + boff);
                }
            }
            // stale lanes keep finite regs; Et zero-pad nullifies their product
        }

        // ---- barrier WITHOUT vmcnt drain (raw s_barrier, lgkm only)
        asm volatile("s_waitcnt lgkmcnt(0)" ::: "memory");
        __builtin_amdgcn_s_barrier();
        asm volatile("" ::: "memory");

        // ---- COMPUTE: wave w covers k-steps 2w, 2w+1 of this chunk
        {
            const int ks0 = 2 * w;
            const int cb0 = 64 * ks0 + 16 * g4;
            const int r0 = dcol, r1 = 16 + dcol;
            const bf16x8 af0 = *(const bf16x8*)(smem + (r0 << 9) + (cb0 ^ ((r0 & 7) << 4)));
            const bf16x8 af1 = *(const bf16x8*)(smem + (r1 << 9) + (cb0 ^ ((r1 & 7) << 4)));

            // issue h=1 Et loads now (covered by h=0 MFMAs + TLP)
            bf16x8 bfr1[4];
            {
                const int kk = kb * KC + (2 * w + 1) * 32 + 8 * g4;
#pragma unroll
                for (int df = 0; df < 4; ++df)
                    bfr1[df] = *(const bf16x8*)(EbBase + df * dfs + kk);
            }

            acc[0] = __builtin_amdgcn_mfma_f32_16x16x32_bf16(af0, bfr0[0], acc[0], 0, 0, 0);
            acc[1] = __builtin_amdgcn_mfma_f32_16x16x32_bf16(af0, bfr0[1], acc[1], 0, 0, 0);
            acc[2] = __builtin_amdgcn_mfma_f32_16x16x32_bf16(af0, bfr0[2], acc[2], 0, 0, 0);
            acc[3] = __builtin_amdgcn_mfma_f32_16x16x32_bf16(af0, bfr0[3], acc[3], 0, 0, 0);
            acc[4] = __builtin_amdgcn_mfma_f32_16x16x32_bf16(af1, bfr0[0], acc[4], 0, 0, 0);
            acc[5] = __builtin_amdgcn_mfma_f32_16x16x32_bf16(af1, bfr0[1], acc[5], 0, 0, 0);
            acc[6] = __builtin_amdgcn_mfma_f32_16x16x32_bf16(af1, bfr0[2], acc[6], 0, 0, 0);
            acc[7] = __builtin_amdgcn_mfma_f32_16x16x32_bf16(af1, bfr0[3], acc[7], 0, 0, 0);

            const int cb1 = 64 * (ks0 + 1) + 16 * g4;
            const bf16x8 ag0 = *(const bf16x8*)(smem + (r0 << 9) + (cb1 ^ ((r0 & 7) << 4)));
            const bf16x8 ag1 = *(const bf16x8*)(smem + (r1 << 9) + (cb1 ^ ((r1 & 7) << 4)));

            acc[0] = __builtin_amdgcn_mfma_f32_16x16x32_bf16(ag0, bfr1[0], acc[0], 0, 0, 0);
            acc[1] = __builtin_amdgcn_mfma_f32_16x16x32_bf16(ag0, bfr1[1], acc[1], 0, 0, 0);
            acc[2] = __builtin_amdgcn_mfma_f32_16x16x32_bf16(ag0, bfr1[2], acc[2], 0, 0, 0);
            acc[3] = __builtin_amdgcn_mfma_f32_16x16x32_bf16(ag0, bfr1[3], acc[3], 0, 0, 0);
            acc[4] = __builtin_amdgcn_mfma_f32_16x16x32_bf16(ag1, bfr1[0], acc[4], 0, 0, 0);
            acc[5] = __builtin_amdgcn_mfma_f32_16x16x32_bf16(ag1, bfr1[1], acc[5], 0, 0, 0);
            acc[6] = __builtin_amdgcn_mfma_f32_16x16x32_bf16(ag1, bfr1[2], acc[6], 0, 0, 0);
            acc[7] = __builtin_amdgcn_mfma_f32_16x16x32_bf16(ag1, bfr1[3], acc[7], 0, 0, 0);
        }

        // ---- protect LDS from next iter's STORE
        asm volatile("" ::: "memory");
        __builtin_amdgcn_s_barrier();
        asm volatile("" ::: "memory");
    }

    // ---- cross-wave reduction: sum the 4 k-quarter accs -> ONE P slice/block
    __syncthreads();                       // done with As region
    float* Rs = (float*)smem;              // [4][32][65] floats, +1 pad stagger
#pragma unroll
    for (int fi = 0; fi < 8; ++fi) {
#pragma unroll
        for (int ri = 0; ri < 4; ++ri) {
            const int row = ((fi >> 2) << 4) + g4 * 4 + ri;
            const int col = ((fi & 3) << 4) + dcol;
            Rs[(w * 32 + row) * 65 + col] = acc[fi][ri];
        }
    }
    __syncthreads();
    {
        const int row  = tid >> 3;         // 0..31
        const int colg = (tid & 7) * 8;    // 0,8,..56
        float v[8];
#pragma unroll
        for (int i = 0; i < 8; ++i) {
            v[i] = Rs[(0 * 32 + row) * 65 + colg + i]
                 + Rs[(1 * 32 + row) * 65 + colg + i]
                 + Rs[(2 * 32 + row) * 65 + colg + i]
                 + Rs[(3 * 32 + row) * 65 + colg + i];
        }
        float* Pb = P + ((size_t)(j * S + s) * BB + base + row) * DD + colg;
        *(float4*)(Pb + 0) = make_float4(v[0], v[1], v[2], v[3]);
        *(float4*)(Pb + 4) = make_float4(v[4], v[5], v[6], v[7]);
    }
}

// ---------------------------------------------------------------------------
// Kernel 2: per-batch-row finalize (4 rows per 256-thread block).
// ---------------------------------------------------------------------------
__global__ __launch_bounds__(256) void gde_finalize(
    const float* __restrict__ P, int Seff,
    float* __restrict__ term, float* __restrict__ regp)
{
    const int b    = blockIdx.x * 4 + (threadIdx.x >> 6);
    const int lane = threadIdx.x & 63;
    const size_t joff = (size_t)Seff * BB * DD;

    float fu = 0.f, fp_ = 0.f, fn = 0.f;
    for (int s = 0; s < Seff; ++s) {
        const size_t base = ((size_t)s * BB + b) * DD + lane;
        fu  += P[base];
        fp_ += P[base + joff];
        fn  += P[base + 2 * joff];
    }

    float rp = fu * fp_;
    float rn = fu * fn;
    float rg = fu * fu + fp_ * fp_ + fn * fn;
#pragma unroll
    for (int o = 32; o > 0; o >>= 1) {
        rp += __shfl_xor(rp, o);
        rn += __shfl_xor(rn, o);
        rg += __shfl_xor(rg, o);
    }

    if (lane == 0) {
        const float sn = 1.0f / (1.0f + expf(-rn));
        const float w  = 1.0f - log10f(1.0f - fminf(sn, 0.99f));
        const float x  = rp - w * rn;
        const float t  = -x;   // -log(sigmoid(x)) = softplus(-x), finite
        term[b] = fmaxf(t, 0.0f) + log1pf(expf(-fabsf(t)));
        regp[b] = rg;
    }
}

// ---------------------------------------------------------------------------
// Kernel 3: deterministic scalar reduction.
// ---------------------------------------------------------------------------
__global__ __launch_bounds__(256) void gde_reduce(
    const float* __restrict__ term, const float* __restrict__ regp,
    float* __restrict__ out)
{
    __shared__ float sm[256];
    const int t = threadIdx.x;
    float v = 0.f;
    for (int i = t; i < BB; i += 256)
        v += term[i] + 0.01f * regp[i];
    sm[t] = v;
    __syncthreads();
    for (int o = 128; o > 0; o >>= 1) {
        if (t < o) sm[t] += sm[t + o];
        __syncthreads();
    }
    if (t == 0) out[0] = sm[0] / (float)BB;
}

extern "C" void kernel_launch(void* const* d_in, const int* in_sizes, int n_in,
                              void* d_out, int out_size, void* d_ws, size_t ws_size,
                              hipStream_t stream)
{
    const float* L_u = (const float*)d_in[0];
    const float* L_i = (const float*)d_in[1];
    const float* ue  = (const float*)d_in[2];
    const float* ie  = (const float*)d_in[3];
    const float* mu  = (const float*)d_in[4];
    const float* mp  = (const float*)d_in[5];
    const float* mn  = (const float*)d_in[6];
    const int* user  = (const int*)d_in[7];
    const int* pos   = (const int*)d_in[8];
    const int* nega  = (const int*)d_in[9];
    float* out = (float*)d_out;

    const size_t etU_b  = (size_t)DD * NPU * 2;
    const size_t etI_b  = (size_t)DD * NPI * 2;
    const size_t slice  = (size_t)3 * BB * DD * 4;    // per-slice P bytes
    const int S = SPL;                                 // 8 slices (6.3 MB), fits ws

    float*    P    = (float*)d_ws;
    ushort_t* EtU  = (ushort_t*)((char*)d_ws + (size_t)S * slice);
    ushort_t* EtI  = (ushort_t*)((char*)EtU + etU_b);
    float*    term = (float*)((char*)EtI + etI_b);
    float*    regp = term + BB;

    gde_transpose<<<dim3(NPU / 64), dim3(256), 0, stream>>>(ue, EtU, NU_, NPU);
    gde_transpose<<<dim3(NPI / 64), dim3(256), 0, stream>>>(ie, EtI, NI_, NPI);

    gde_gemm<<<dim3(32 * SPL * 3), dim3(256), 0, stream>>>(
        L_u, L_i, EtU, EtI, mu, mp, mn, user, pos, nega, P, S);

    gde_finalize<<<dim3(BB / 4), dim3(256), 0, stream>>>(P, S, term, regp);
    gde_reduce<<<dim3(1), dim3(256), 0, stream>>>(term, regp, out);
}